// Round 4
// baseline (1449.383 us; speedup 1.0000x reference)
//
#include <hip/hip_runtime.h>

// Problem constants (from reference)
#define N_U 100000
#define N_V 100000
#define OO 64
#define RR 5
#define EE 500000

typedef short bf16x8 __attribute__((ext_vector_type(8)));
typedef float f32x4 __attribute__((ext_vector_type(4)));

__device__ __forceinline__ float bf2f(unsigned short u) {
  union { unsigned int i; float f; } x;
  x.i = ((unsigned int)u) << 16;
  return x.f;
}
__device__ __forceinline__ unsigned short f2bf(float f) {
  union { float f; unsigned int i; } x;
  x.f = f;
  unsigned int lsb = (x.i >> 16) & 1u;
  unsigned int r = x.i + 0x7fffu + lsb;   // round-to-nearest-even
  return (unsigned short)(r >> 16);
}

// ---------------------------------------------------------------------------
// Cumsum the per-relation fp32 weights, write bf16 in MFMA B-fragment order:
// frag f = col_tile*2 + k_half, 8 contiguous bf16 per lane:
//   B[k = khalf*32 + (lane>>4)*8 + j][n = 16*ctile + (lane&15)]
// bfrag layout: [side(2)][r(5)][4096]
// ---------------------------------------------------------------------------
__global__ void prep_weights(const float* __restrict__ wu,
                             const float* __restrict__ wv,
                             unsigned short* __restrict__ bfrag) {
  int side = blockIdx.x;            // 0 = u, 1 = v
  const float* w = side ? wv : wu;
  for (int idx = threadIdx.x; idx < 4096; idx += 256) {
    int d = idx >> 6, o = idx & 63;
    int c = o >> 4, n = o & 15;
    int sk = d >> 5, q = (d >> 3) & 3, jj = d & 7;
    int f = c * 2 + sk;
    int lane = q * 16 + n;
    int pos = (f * 64 + lane) * 8 + jj;
    float acc = 0.f;
    for (int r = 0; r < RR; ++r) {
      acc += w[r * 4096 + idx];
      bfrag[(side * RR + r) * 4096 + pos] = f2bf(acc);
    }
  }
}

// ---------------------------------------------------------------------------
// tmp = X @ Wcum  (M=100000, K=64, N=64). fp32 X -> bf16 frags -> MFMA,
// bf16 tmp out. One wave per 16-row tile; B fragments in VGPRs.
// 100000 = 16*6250; grid 1563*4 = 6252 waves, guarded.
// ---------------------------------------------------------------------------
__global__ __launch_bounds__(256) void gemm_kernel(
    const float* __restrict__ X,
    const unsigned short* __restrict__ bfrag,
    unsigned short* __restrict__ tmp) {
  int lane = threadIdx.x & 63;
  int wave = threadIdx.x >> 6;
  int q = lane >> 4, m = lane & 15;

  bf16x8 bf[8];
#pragma unroll
  for (int f = 0; f < 8; ++f)
    bf[f] = *(const bf16x8*)(bfrag + (f * 64 + lane) * 8);

  int t = blockIdx.x * 4 + wave;
  if (t >= N_U / 16) return;
  int r0 = t * 16;

  const float* xr = X + (size_t)(r0 + m) * 64;
  float4 p0 = *(const float4*)(xr + q * 8);
  float4 p1 = *(const float4*)(xr + q * 8 + 4);
  float4 p2 = *(const float4*)(xr + 32 + q * 8);
  float4 p3 = *(const float4*)(xr + 32 + q * 8 + 4);
  bf16x8 a0, a1;
  a0[0] = (short)f2bf(p0.x); a0[1] = (short)f2bf(p0.y);
  a0[2] = (short)f2bf(p0.z); a0[3] = (short)f2bf(p0.w);
  a0[4] = (short)f2bf(p1.x); a0[5] = (short)f2bf(p1.y);
  a0[6] = (short)f2bf(p1.z); a0[7] = (short)f2bf(p1.w);
  a1[0] = (short)f2bf(p2.x); a1[1] = (short)f2bf(p2.y);
  a1[2] = (short)f2bf(p2.z); a1[3] = (short)f2bf(p2.w);
  a1[4] = (short)f2bf(p3.x); a1[5] = (short)f2bf(p3.y);
  a1[6] = (short)f2bf(p3.z); a1[7] = (short)f2bf(p3.w);

#pragma unroll
  for (int c = 0; c < 4; ++c) {
    f32x4 acc = {0.f, 0.f, 0.f, 0.f};
    acc = __builtin_amdgcn_mfma_f32_16x16x32_bf16(a0, bf[c * 2 + 0], acc, 0, 0, 0);
    acc = __builtin_amdgcn_mfma_f32_16x16x32_bf16(a1, bf[c * 2 + 1], acc, 0, 0, 0);
#pragma unroll
    for (int i = 0; i < 4; ++i) {
      // C/D layout: col = lane&15 (+16c), row = quad*4 + i
      tmp[(size_t)(r0 + q * 4 + i) * 64 + c * 16 + m] = f2bf(acc[i]);
    }
  }
}

// ---------------------------------------------------------------------------
// One direction of edge scatter for one relation, dst-range-filtered:
// z[dst-base] += val * tmp[src] for dst in [base, base+cnt).
// 64 lanes per edge, 4 edges per block. 500000 % 4 == 0 -> no tail guard.
// ---------------------------------------------------------------------------
__global__ __launch_bounds__(256) void scatter_kernel(
    const unsigned short* __restrict__ tmp,
    const float* __restrict__ edge_val,
    const int* __restrict__ dst_idx, const int* __restrict__ src_idx,
    float* __restrict__ z, int base, int cnt) {
  int e = blockIdx.x * 4 + (threadIdx.x >> 6);
  int j = threadIdx.x & 63;
  int d = dst_idx[e] - base;
  if ((unsigned)d >= (unsigned)cnt) return;
  int s = src_idx[e];
  float w = edge_val[e];
  atomicAdd(&z[(size_t)d * 64 + j], w * bf2f(tmp[(size_t)s * 64 + j]));
}

// ---------------------------------------------------------------------------
// out = relu(z + bias) -> fp32. cnt*64 elements (cnt % 16 == 0), 4/thread.
// ---------------------------------------------------------------------------
__global__ __launch_bounds__(256) void finalize_kernel(
    const float* __restrict__ z, const float* __restrict__ bias,
    float* __restrict__ out) {
  size_t i4 = ((size_t)blockIdx.x * 256 + threadIdx.x) * 4;
  float4 zz = *(const float4*)(z + i4);
  const float4 bb = *(const float4*)(bias + (i4 & 63));
  float4 o;
  o.x = fmaxf(zz.x + bb.x, 0.f);
  o.y = fmaxf(zz.y + bb.y, 0.f);
  o.z = fmaxf(zz.z + bb.z, 0.f);
  o.w = fmaxf(zz.w + bb.w, 0.f);
  *(float4*)(out + i4) = o;
}

extern "C" void kernel_launch(void* const* d_in, const int* in_sizes, int n_in,
                              void* d_out, int out_size, void* d_ws, size_t ws_size,
                              hipStream_t stream) {
  const float* x_u      = (const float*)d_in[0];
  const float* x_v      = (const float*)d_in[1];
  const float* w_u      = (const float*)d_in[2];
  const float* w_v      = (const float*)d_in[3];
  const float* bias_u   = (const float*)d_in[4];
  const float* bias_v   = (const float*)d_in[5];
  const float* edge_val = (const float*)d_in[6];
  const int*   edge_u   = (const int*)d_in[7];
  const int*   edge_v   = (const int*)d_in[8];
  float* out = (float*)d_out;

  // ws layout (adaptive):
  //   bfrag @ 0        : 2*5*4096*2 = 81,920 B (padded to 131,072)
  //   tmp   @ 131072   : 100000*64*2 = 12,800,000 B (bf16, reused per (side,r))
  //   z     @ 12931072 : fp32 accumulator chunk, whatever fits
  char* ws = (char*)d_ws;
  unsigned short* bfrag = (unsigned short*)(ws);
  unsigned short* tmp   = (unsigned short*)(ws + 131072);
  float*          z     = (float*)(ws + 131072 + 12800000);
  const size_t fixed = 131072 + 12800000;

  size_t zbytes = ws_size > fixed ? ws_size - fixed : 0;
  long chunk = (long)(zbytes / (OO * 4));   // nodes per z chunk
  chunk -= chunk % 16;
  if (chunk < 16) chunk = 16;               // (ws too small -> best effort)
  if (chunk > N_U) chunk = N_U;

  prep_weights<<<2, 256, 0, stream>>>(w_u, w_v, bfrag);

  const int gemm_grid = (N_U / 16 + 3) / 4;   // 1563
  const int scat_grid = EE / 4;               // 125000

  for (int side = 0; side < 2; ++side) {
    // side 0: z_u, gather from item rows (tmp of x_v @ Wcum_v), dst=edge_u
    // side 1: z_v, gather from user rows (tmp of x_u @ Wcum_u), dst=edge_v
    const float* X = side ? x_u : x_v;
    const unsigned short* frag0 = bfrag + (side ? 0 : RR * 4096);
    const int* dst = side ? edge_v : edge_u;
    const int* src = side ? edge_u : edge_v;
    const float* bias = side ? bias_v : bias_u;
    float* out_side = out + (size_t)side * N_U * OO;

    for (long base = 0; base < N_U; base += chunk) {
      long cnt = N_U - base < chunk ? N_U - base : chunk;
      hipMemsetAsync(z, 0, (size_t)cnt * OO * 4, stream);
      for (int r = 0; r < RR; ++r) {
        gemm_kernel<<<gemm_grid, 256, 0, stream>>>(X, frag0 + r * 4096, tmp);
        scatter_kernel<<<scat_grid, 256, 0, stream>>>(
            tmp, edge_val + (size_t)r * EE, dst + (size_t)r * EE,
            src + (size_t)r * EE, z, (int)base, (int)cnt);
      }
      finalize_kernel<<<(int)(cnt / 16), 256, 0, stream>>>(
          z, bias, out_side + base * OO);
    }
  }
}

// Round 5
// 1070.992 us; speedup vs baseline: 1.3533x; 1.3533x over previous
//
#include <hip/hip_runtime.h>

// Problem constants (from reference)
#define N_U 100000
#define N_V 100000
#define OO 64
#define RR 5
#define EE 500000
#define TOT_E (RR * EE)   // 2,500,000 edges per direction

typedef short bf16x8 __attribute__((ext_vector_type(8)));
typedef float f32x4 __attribute__((ext_vector_type(4)));

__device__ __forceinline__ float bf2f(unsigned short u) {
  union { unsigned int i; float f; } x;
  x.i = ((unsigned int)u) << 16;
  return x.f;
}
__device__ __forceinline__ unsigned short f2bf(float f) {
  union { float f; unsigned int i; } x;
  x.f = f;
  unsigned int lsb = (x.i >> 16) & 1u;
  unsigned int r = x.i + 0x7fffu + lsb;   // round-to-nearest-even
  return (unsigned short)(r >> 16);
}

// ---------------------------------------------------------------------------
// Cumsum the per-relation fp32 weights, write bf16 in MFMA B-fragment order:
// frag f = col_tile*2 + k_half, 8 contiguous bf16 per lane:
//   B[k = khalf*32 + (lane>>4)*8 + j][n = 16*ctile + (lane&15)]
// bfrag layout: [side(2)=u,v][r(5)][4096]
// ---------------------------------------------------------------------------
__global__ void prep_weights(const float* __restrict__ wu,
                             const float* __restrict__ wv,
                             unsigned short* __restrict__ bfrag) {
  int side = blockIdx.x;
  const float* w = side ? wv : wu;
  for (int idx = threadIdx.x; idx < 4096; idx += 256) {
    int d = idx >> 6, o = idx & 63;
    int c = o >> 4, n = o & 15;
    int sk = d >> 5, q = (d >> 3) & 3, jj = d & 7;
    int f = c * 2 + sk;
    int lane = q * 16 + n;
    int pos = (f * 64 + lane) * 8 + jj;
    float acc = 0.f;
    for (int r = 0; r < RR; ++r) {
      acc += w[r * 4096 + idx];
      bfrag[(side * RR + r) * 4096 + pos] = f2bf(acc);
    }
  }
}

// ===========================================================================
// FAST PATH
// ===========================================================================

// ---------------------------------------------------------------------------
// All-5-relations GEMM: tmp[r] = X @ Wcum[r]. A-frags are r-independent, so X
// is read once. B frags staged in LDS (40 KB). tmp rows stored in lane-perm
// layout: tmp_r[row*64 + m*4 + c] = D[row][c*16+m]  (8 B/lane stores).
// One wave per 16-row tile; grid 1563*4 = 6252 waves for 6250 tiles.
// ---------------------------------------------------------------------------
__global__ __launch_bounds__(256) void gemm5_kernel(
    const float* __restrict__ X,
    const unsigned short* __restrict__ bfrag_side,  // [r(5)][4096]
    unsigned short* __restrict__ tmp5) {            // [r(5)][100000][64]
  __shared__ unsigned short smem[RR * 4096];
  for (int idx = threadIdx.x; idx < RR * 4096; idx += 256)
    smem[idx] = bfrag_side[idx];
  __syncthreads();

  int lane = threadIdx.x & 63;
  int wave = threadIdx.x >> 6;
  int q = lane >> 4, m = lane & 15;
  int t = blockIdx.x * 4 + wave;
  if (t >= N_U / 16) return;
  int r0 = t * 16;

  const float* xr = X + (size_t)(r0 + m) * 64;
  float4 p0 = *(const float4*)(xr + q * 8);
  float4 p1 = *(const float4*)(xr + q * 8 + 4);
  float4 p2 = *(const float4*)(xr + 32 + q * 8);
  float4 p3 = *(const float4*)(xr + 32 + q * 8 + 4);
  bf16x8 a0, a1;
  a0[0] = (short)f2bf(p0.x); a0[1] = (short)f2bf(p0.y);
  a0[2] = (short)f2bf(p0.z); a0[3] = (short)f2bf(p0.w);
  a0[4] = (short)f2bf(p1.x); a0[5] = (short)f2bf(p1.y);
  a0[6] = (short)f2bf(p1.z); a0[7] = (short)f2bf(p1.w);
  a1[0] = (short)f2bf(p2.x); a1[1] = (short)f2bf(p2.y);
  a1[2] = (short)f2bf(p2.z); a1[3] = (short)f2bf(p2.w);
  a1[4] = (short)f2bf(p3.x); a1[5] = (short)f2bf(p3.y);
  a1[6] = (short)f2bf(p3.z); a1[7] = (short)f2bf(p3.w);

  for (int r = 0; r < RR; ++r) {
    f32x4 acc[4];
#pragma unroll
    for (int c = 0; c < 4; ++c) {
      bf16x8 b0 = *(const bf16x8*)(smem + r * 4096 + ((c * 2 + 0) * 64 + lane) * 8);
      bf16x8 b1 = *(const bf16x8*)(smem + r * 4096 + ((c * 2 + 1) * 64 + lane) * 8);
      f32x4 a = {0.f, 0.f, 0.f, 0.f};
      a = __builtin_amdgcn_mfma_f32_16x16x32_bf16(a0, b0, a, 0, 0, 0);
      a = __builtin_amdgcn_mfma_f32_16x16x32_bf16(a1, b1, a, 0, 0, 0);
      acc[c] = a;
    }
    unsigned short* trow = tmp5 + (size_t)r * N_U * 64;
#pragma unroll
    for (int i = 0; i < 4; ++i) {
      ushort4 o;
      o.x = f2bf(acc[0][i]); o.y = f2bf(acc[1][i]);
      o.z = f2bf(acc[2][i]); o.w = f2bf(acc[3][i]);
      *(ushort4*)(trow + (size_t)(r0 + q * 4 + i) * 64 + m * 4) = o;
    }
  }
}

// Histogram of dst indices into cursor[100000] (pre-zeroed).
__global__ __launch_bounds__(256) void hist_kernel(
    const int* __restrict__ dst, unsigned* __restrict__ cursor) {
  int e = blockIdx.x * 256 + threadIdx.x;
  if (e >= TOT_E) return;
  atomicAdd(&cursor[dst[e]], 1u);
}

// Scan pass A: per-1024-item block sums -> partials[98]
__global__ __launch_bounds__(256) void scan_a_kernel(
    const unsigned* __restrict__ cursor, unsigned* __restrict__ part) {
  __shared__ unsigned red[4];
  int lane = threadIdx.x & 63, wave = threadIdx.x >> 6;
  int i0 = blockIdx.x * 1024 + threadIdx.x * 4;
  unsigned s = 0;
#pragma unroll
  for (int k = 0; k < 4; ++k)
    if (i0 + k < N_U) s += cursor[i0 + k];
#pragma unroll
  for (int d = 32; d >= 1; d >>= 1) s += __shfl_down(s, d);
  if (lane == 0) red[wave] = s;
  __syncthreads();
  if (threadIdx.x == 0)
    part[blockIdx.x] = red[0] + red[1] + red[2] + red[3];
}

// Scan pass B: serial exclusive scan of 98 partials; writes offs[N_U]=TOT_E.
__global__ void scan_b_kernel(unsigned* __restrict__ part,
                              unsigned* __restrict__ offs) {
  if (threadIdx.x == 0) {
    unsigned s = 0;
    for (int i = 0; i < 98; ++i) { unsigned c = part[i]; part[i] = s; s += c; }
    offs[N_U] = TOT_E;
  }
}

// Scan pass C: per-block exclusive scan of 1024 counts + partial base.
// Writes offs[i] and initializes cursor[i] = offs[i] for the fill pass.
__global__ __launch_bounds__(256) void scan_c_kernel(
    unsigned* __restrict__ cursor, const unsigned* __restrict__ part,
    unsigned* __restrict__ offs) {
  __shared__ unsigned wt[4];
  int lane = threadIdx.x & 63, wave = threadIdx.x >> 6;
  int i0 = blockIdx.x * 1024 + threadIdx.x * 4;
  unsigned c[4];
  unsigned s = 0;
#pragma unroll
  for (int k = 0; k < 4; ++k) {
    c[k] = (i0 + k < N_U) ? cursor[i0 + k] : 0u;
    s += c[k];
  }
  unsigned incl = s;
#pragma unroll
  for (int d = 1; d < 64; d <<= 1) {
    unsigned t = __shfl_up(incl, d);
    if (lane >= d) incl += t;
  }
  if (lane == 63) wt[wave] = incl;
  __syncthreads();
  unsigned woff = 0;
  for (int w = 0; w < 4; ++w) if (w < wave) woff += wt[w];
  unsigned base = part[blockIdx.x] + woff + (incl - s);
#pragma unroll
  for (int k = 0; k < 4; ++k) {
    if (i0 + k < N_U) { offs[i0 + k] = base; cursor[i0 + k] = base; }
    base += c[k];
  }
}

// Fill: payload[pos] = (val_bits<<32) | (r<<20) | src, pos via cursor bump.
__global__ __launch_bounds__(256) void fill_kernel(
    const int* __restrict__ dst, const int* __restrict__ src,
    const float* __restrict__ val, unsigned* __restrict__ cursor,
    unsigned long long* __restrict__ payload) {
  int e = blockIdx.x * 256 + threadIdx.x;
  if (e >= TOT_E) return;
  int d = dst[e];
  unsigned key = (unsigned)((e / EE) << 20) | (unsigned)src[e];
  union { float f; unsigned u; } v; v.f = val[e];
  unsigned pos = atomicAdd(&cursor[d], 1u);
  payload[pos] = ((unsigned long long)v.u << 32) | key;
}

// Aggregate: one wave per dst node; lane j owns output col j.
// tmp row layout is lane-permuted: col j lives at position (j&15)*4 + (j>>4).
__global__ __launch_bounds__(256) void aggregate_kernel(
    const unsigned long long* __restrict__ payload,
    const unsigned* __restrict__ offs,
    const unsigned short* __restrict__ tmp5,
    const float* __restrict__ bias, float* __restrict__ out) {
  int lane = threadIdx.x & 63;
  int wave = threadIdx.x >> 6;
  int node = blockIdx.x * 4 + wave;          // 25000*4 == 100000 exactly
  int start = (int)offs[node], end = (int)offs[node + 1];
  int ppos = (lane & 15) * 4 + (lane >> 4);
  float acc = 0.f;
  int k = start;
  for (; k + 1 < end; k += 2) {
    unsigned long long p0 = payload[k], p1 = payload[k + 1];
    unsigned k0 = (unsigned)p0, k1 = (unsigned)p1;
    union { unsigned u; float f; } v0, v1;
    v0.u = (unsigned)(p0 >> 32); v1.u = (unsigned)(p1 >> 32);
    float t0 = bf2f(tmp5[((size_t)(k0 >> 20) * N_U + (k0 & 0xFFFFFu)) * 64 + ppos]);
    float t1 = bf2f(tmp5[((size_t)(k1 >> 20) * N_U + (k1 & 0xFFFFFu)) * 64 + ppos]);
    acc += v0.f * t0;
    acc += v1.f * t1;
  }
  if (k < end) {
    unsigned long long p0 = payload[k];
    unsigned k0 = (unsigned)p0;
    union { unsigned u; float f; } v0; v0.u = (unsigned)(p0 >> 32);
    acc += v0.f * bf2f(tmp5[((size_t)(k0 >> 20) * N_U + (k0 & 0xFFFFFu)) * 64 + ppos]);
  }
  out[(size_t)node * 64 + lane] = fmaxf(acc + bias[lane], 0.f);
}

// ===========================================================================
// FALLBACK PATH (proven R4 atomic-scatter version, used if ws is small)
// ===========================================================================
__global__ __launch_bounds__(256) void gemm_kernel(
    const float* __restrict__ X, const unsigned short* __restrict__ bfrag,
    unsigned short* __restrict__ tmp) {
  int lane = threadIdx.x & 63;
  int wave = threadIdx.x >> 6;
  int q = lane >> 4, m = lane & 15;
  bf16x8 bf[8];
#pragma unroll
  for (int f = 0; f < 8; ++f)
    bf[f] = *(const bf16x8*)(bfrag + (f * 64 + lane) * 8);
  int t = blockIdx.x * 4 + wave;
  if (t >= N_U / 16) return;
  int r0 = t * 16;
  const float* xr = X + (size_t)(r0 + m) * 64;
  float4 p0 = *(const float4*)(xr + q * 8);
  float4 p1 = *(const float4*)(xr + q * 8 + 4);
  float4 p2 = *(const float4*)(xr + 32 + q * 8);
  float4 p3 = *(const float4*)(xr + 32 + q * 8 + 4);
  bf16x8 a0, a1;
  a0[0] = (short)f2bf(p0.x); a0[1] = (short)f2bf(p0.y);
  a0[2] = (short)f2bf(p0.z); a0[3] = (short)f2bf(p0.w);
  a0[4] = (short)f2bf(p1.x); a0[5] = (short)f2bf(p1.y);
  a0[6] = (short)f2bf(p1.z); a0[7] = (short)f2bf(p1.w);
  a1[0] = (short)f2bf(p2.x); a1[1] = (short)f2bf(p2.y);
  a1[2] = (short)f2bf(p2.z); a1[3] = (short)f2bf(p2.w);
  a1[4] = (short)f2bf(p3.x); a1[5] = (short)f2bf(p3.y);
  a1[6] = (short)f2bf(p3.z); a1[7] = (short)f2bf(p3.w);
#pragma unroll
  for (int c = 0; c < 4; ++c) {
    f32x4 acc = {0.f, 0.f, 0.f, 0.f};
    acc = __builtin_amdgcn_mfma_f32_16x16x32_bf16(a0, bf[c * 2 + 0], acc, 0, 0, 0);
    acc = __builtin_amdgcn_mfma_f32_16x16x32_bf16(a1, bf[c * 2 + 1], acc, 0, 0, 0);
#pragma unroll
    for (int i = 0; i < 4; ++i)
      tmp[(size_t)(r0 + q * 4 + i) * 64 + c * 16 + m] = f2bf(acc[i]);
  }
}

__global__ __launch_bounds__(256) void scatter_kernel(
    const unsigned short* __restrict__ tmp, const float* __restrict__ edge_val,
    const int* __restrict__ dst_idx, const int* __restrict__ src_idx,
    float* __restrict__ z, int base, int cnt) {
  int e = blockIdx.x * 4 + (threadIdx.x >> 6);
  int j = threadIdx.x & 63;
  int d = dst_idx[e] - base;
  if ((unsigned)d >= (unsigned)cnt) return;
  int s = src_idx[e];
  float w = edge_val[e];
  atomicAdd(&z[(size_t)d * 64 + j], w * bf2f(tmp[(size_t)s * 64 + j]));
}

__global__ __launch_bounds__(256) void finalize_kernel(
    const float* __restrict__ z, const float* __restrict__ bias,
    float* __restrict__ out) {
  size_t i4 = ((size_t)blockIdx.x * 256 + threadIdx.x) * 4;
  float4 zz = *(const float4*)(z + i4);
  const float4 bb = *(const float4*)(bias + (i4 & 63));
  float4 o;
  o.x = fmaxf(zz.x + bb.x, 0.f);
  o.y = fmaxf(zz.y + bb.y, 0.f);
  o.z = fmaxf(zz.z + bb.z, 0.f);
  o.w = fmaxf(zz.w + bb.w, 0.f);
  *(float4*)(out + i4) = o;
}

extern "C" void kernel_launch(void* const* d_in, const int* in_sizes, int n_in,
                              void* d_out, int out_size, void* d_ws, size_t ws_size,
                              hipStream_t stream) {
  const float* x_u      = (const float*)d_in[0];
  const float* x_v      = (const float*)d_in[1];
  const float* w_u      = (const float*)d_in[2];
  const float* w_v      = (const float*)d_in[3];
  const float* bias_u   = (const float*)d_in[4];
  const float* bias_v   = (const float*)d_in[5];
  const float* edge_val = (const float*)d_in[6];
  const int*   edge_u   = (const int*)d_in[7];
  const int*   edge_v   = (const int*)d_in[8];
  float* out = (float*)d_out;
  char* ws = (char*)d_ws;

  // Fast-path ws layout:
  //   bfrag   @ 0           131,072 (uses 81,920)
  //   tmp5    @ 131,072     5*100000*64*2 = 64,000,000
  //   offs    @ 64,131,072  100001 u32 -> padded 401,408
  //   cursor  @ 64,532,480  100000 u32 -> padded 401,408
  //   part    @ 64,933,888  98 u32 -> padded 2,048
  //   payload @ 64,935,936  2,500,000 * 8 = 20,000,000  -> end 84,935,936
  const size_t FAST_NEED = 84935936;

  unsigned short* bfrag = (unsigned short*)ws;
  prep_weights<<<2, 256, 0, stream>>>(w_u, w_v, bfrag);

  if (ws_size >= FAST_NEED) {
    unsigned short* tmp5   = (unsigned short*)(ws + 131072);
    unsigned*       offs   = (unsigned*)(ws + 64131072);
    unsigned*       cursor = (unsigned*)(ws + 64532480);
    unsigned*       part   = (unsigned*)(ws + 64933888);
    unsigned long long* payload = (unsigned long long*)(ws + 64935936);

    const int hist_grid = (TOT_E + 255) / 256;   // 9766
    const int scan_grid = (N_U + 1023) / 1024;   // 98
    const int gemm_grid = (N_U / 16 + 3) / 4;    // 1563
    const int agg_grid  = N_U / 4;               // 25000

    for (int side = 0; side < 2; ++side) {
      // side 0: z_u <- tmp of x_v @ Wcum_v, dst=edge_u, src=edge_v
      // side 1: z_v <- tmp of x_u @ Wcum_u, dst=edge_v, src=edge_u
      const float* X = side ? x_u : x_v;
      const unsigned short* frag0 = bfrag + (side ? 0 : RR * 4096);
      const int* dst = side ? edge_v : edge_u;
      const int* src = side ? edge_u : edge_v;
      const float* bias = side ? bias_v : bias_u;
      float* out_side = out + (size_t)side * N_U * OO;

      gemm5_kernel<<<gemm_grid, 256, 0, stream>>>(X, frag0, tmp5);
      hipMemsetAsync(cursor, 0, N_U * 4, stream);
      hist_kernel<<<hist_grid, 256, 0, stream>>>(dst, cursor);
      scan_a_kernel<<<scan_grid, 256, 0, stream>>>(cursor, part);
      scan_b_kernel<<<1, 64, 0, stream>>>(part, offs);
      scan_c_kernel<<<scan_grid, 256, 0, stream>>>(cursor, part, offs);
      fill_kernel<<<hist_grid, 256, 0, stream>>>(dst, src, edge_val, cursor, payload);
      aggregate_kernel<<<agg_grid, 256, 0, stream>>>(payload, offs, tmp5, bias, out_side);
    }
    return;
  }

  // ---------------- Fallback: proven R4 path ----------------
  unsigned short* tmp = (unsigned short*)(ws + 131072);
  float*          z   = (float*)(ws + 131072 + 12800000);
  const size_t fixed = 131072 + 12800000;
  size_t zbytes = ws_size > fixed ? ws_size - fixed : 0;
  long chunk = (long)(zbytes / (OO * 4));
  chunk -= chunk % 16;
  if (chunk < 16) chunk = 16;
  if (chunk > N_U) chunk = N_U;

  const int gemm_grid = (N_U / 16 + 3) / 4;
  const int scat_grid = EE / 4;

  for (int side = 0; side < 2; ++side) {
    const float* X = side ? x_u : x_v;
    const unsigned short* frag0 = bfrag + (side ? 0 : RR * 4096);
    const int* dst = side ? edge_v : edge_u;
    const int* src = side ? edge_u : edge_v;
    const float* bias = side ? bias_v : bias_u;
    float* out_side = out + (size_t)side * N_U * OO;

    for (long base = 0; base < N_U; base += chunk) {
      long cnt = N_U - base < chunk ? N_U - base : chunk;
      hipMemsetAsync(z, 0, (size_t)cnt * OO * 4, stream);
      for (int r = 0; r < RR; ++r) {
        gemm_kernel<<<gemm_grid, 256, 0, stream>>>(X, frag0 + r * 4096, tmp);
        scatter_kernel<<<scat_grid, 256, 0, stream>>>(
            tmp, edge_val + (size_t)r * EE, dst + (size_t)r * EE,
            src + (size_t)r * EE, z, (int)base, (int)cnt);
      }
      finalize_kernel<<<(int)(cnt / 16), 256, 0, stream>>>(
          z, bias, out_side + base * OO);
    }
  }
}